// Round 11
// baseline (117.581 us; speedup 1.0000x reference)
//
#include <hip/hip_runtime.h>
#include <hip/hip_bf16.h>

typedef float fx4 __attribute__((ext_vector_type(4)));
typedef short i16x8 __attribute__((ext_vector_type(8)));
typedef unsigned short u16;

#define NEG_INF_F (-9.0e15f)

__device__ inline u16 f2bf(float v){
  __hip_bfloat16 h = __float2bfloat16(v);
  return *reinterpret_cast<u16*>(&h);
}
__device__ inline unsigned pk2(float lo, float hi){
  return (unsigned)f2bf(lo) | ((unsigned)f2bf(hi) << 16);
}

// ---------------------------------------------------------------------------
// Kernel 1: Wh = x @ W (fp32), f1 = Wh@a1, f2 = Wh@a2 (fp32).
// Wh emitted bf16 in MFMA B-fragment-linear layout whB[bt][kt][ct][lane][8].
// grid (2, 96), 256 threads; thread = one node n.  (proven, unchanged)
// ---------------------------------------------------------------------------
__global__ __launch_bounds__(256) void gat_prep(
    const float* __restrict__ input,   // (8,64,12,512)
    const float* __restrict__ W,       // (64,64)
    const float* __restrict__ Avec,    // (128,1)
    u16*   __restrict__ whB,           // (96,16,4,512) bf16 fragment-linear
    float* __restrict__ f1w,           // (96,512)
    float* __restrict__ f2w)           // (96,512)
{
  __shared__ float Wl[64*64];
  __shared__ float Al[128];
  __shared__ u16   Rp[16384];
  const int tid = threadIdx.x;
  const int bt  = blockIdx.y;
  const int b   = bt / 12, t = bt % 12;
  const int xb  = blockIdx.x;
  const int n   = xb * 256 + tid;

  {
    const fx4* src = (const fx4*)W;
    fx4* dst = (fx4*)Wl;
    #pragma unroll
    for (int i = 0; i < 4; ++i) dst[tid + 256*i] = src[tid + 256*i];
    if (tid < 32) ((fx4*)Al)[tid] = ((const fx4*)Avec)[tid];
  }
  __syncthreads();

  const float* xp = input + ((size_t)b*64*12 + t) * 512 + n;

  fx4 acc[16];
  #pragma unroll
  for (int i = 0; i < 16; ++i) acc[i] = (fx4){0.f,0.f,0.f,0.f};

  #pragma unroll 8
  for (int f = 0; f < 64; ++f) {
    float xv = xp[(size_t)f * 6144];
    const fx4* wr = (const fx4*)(Wl + f*64);
    #pragma unroll
    for (int o4 = 0; o4 < 16; ++o4) acc[o4] += xv * wr[o4];
  }

  float s1 = 0.f, s2 = 0.f;
  #pragma unroll
  for (int o4 = 0; o4 < 16; ++o4) {
    fx4 v  = acc[o4];
    fx4 w1 = ((const fx4*)Al)[o4];
    fx4 w2 = ((const fx4*)Al)[o4 + 16];
    s1 += v[0]*w1[0] + v[1]*w1[1] + v[2]*w1[2] + v[3]*w1[3];
    s2 += v[0]*w2[0] + v[1]*w2[1] + v[2]*w2[2] + v[3]*w2[3];
  }
  f1w[bt*512 + n] = s1;
  f2w[bt*512 + n] = s2;

  const int ktl  = (n >> 5) & 7;
  const int q    = (n >> 3) & 3;
  const int e    = n & 7;
  const int rowb = ktl*2048 + q*128 + e;
  #pragma unroll
  for (int o4 = 0; o4 < 16; ++o4) {
    #pragma unroll
    for (int c = 0; c < 4; ++c) {
      const int o = o4*4 + c;
      Rp[rowb + (o >> 4)*512 + (o & 15)*8] = f2bf(acc[o4][c]);
    }
  }
  __syncthreads();

  uint4* dst = (uint4*)(whB + ((size_t)bt*16 + xb*8) * 2048);
  const uint4* src = (const uint4*)Rp;
  #pragma unroll
  for (int i = 0; i < 8; ++i) dst[tid + 256*i] = src[tid + 256*i];
}

// ---------------------------------------------------------------------------
// Kernel 2: barrier-free wave-autonomous attn.
// grid 768 (96 bt x 8 chunks), 256 threads = 4 waves; wave owns 16 rows
// end-to-end. After a 2-barrier table prologue, waves never sync: each wave
// loads its own 32KB adj slice (pipelined uint4 rounds -> wave-private
// stride-17 mask words in LDS), then runs a fused per-kt loop where p is
// computed DIRECTLY in MFMA A-fragment layout (lane r,q = row r, cols
// kt*32+8q..+7) and consumed immediately by 4 PV MFMAs + 1 ones-MFMA (row
// sums, delivered in the exact C/D lanes the epilogue needs). Fast path:
// p = max(u*v_j, uh*vh_j) (exact lrelu/exp algebra); rows whose MFMA sum
// < 1e-30 (underflow risk / all-masked; ~never) redo the tile exactly.
// ---------------------------------------------------------------------------
__global__ __launch_bounds__(256, 4) void gat_attn(
    const int*   __restrict__ adj,   // (96,512,512)
    const u16*   __restrict__ whB,   // (96,16,4,512) bf16 fragment-linear
    const float* __restrict__ f1w,
    const float* __restrict__ f2w,
    float*       __restrict__ out)   // (96,512,64)
{
  __shared__ float ve[512], vhe[512], f2l[512];
  __shared__ float f1l[64];
  __shared__ float wmaxl[4];
  __shared__ uint2 lutl[16];
  __shared__ unsigned maskws[4*272];   // per-wave [kt][row] u32, stride 17

  const int tid = threadIdx.x;
  const int l   = tid & 63;
  const int w   = tid >> 6;
  const int id  = blockIdx.x;
  const int bt  = id >> 3;
  const int g0  = (id & 7) * 64;       // block row base within bt
  const int r   = l & 15, q = l >> 4;

  // ---- issue first 2 adj rounds immediately (hide under prologue) --------
  const uint4* ablk = (const uint4*)(adj + ((size_t)bt*512 + g0 + w*16)*512);
  uint4 A0[8], A1[8];
  #pragma unroll
  for (int i = 0; i < 8; ++i) A0[i] = ablk[l*8 + i];
  #pragma unroll
  for (int i = 0; i < 8; ++i) A1[i] = ablk[512 + l*8 + i];

  // ---- prologue: f2 (+block max), f1, LUT; then exp tables ---------------
  float2 fv = ((const float2*)(f2w + bt*512))[tid];
  ((float2*)f2l)[tid] = fv;
  float m2 = fmaxf(fv.x, fv.y);
  #pragma unroll
  for (int off = 32; off >= 1; off >>= 1) m2 = fmaxf(m2, __shfl_xor(m2, off));
  if (l == 0) wmaxl[w] = m2;
  if (tid < 64) f1l[tid] = f1w[bt*512 + g0 + tid];
  if (tid < 16) {
    const unsigned nb = tid;
    lutl[tid] = (uint2){ ((nb&1u)?0xFFFFu:0u) | ((nb&2u)?0xFFFF0000u:0u),
                         ((nb&4u)?0xFFFFu:0u) | ((nb&8u)?0xFFFF0000u:0u) };
  }
  __syncthreads();
  const float F2max = fmaxf(fmaxf(wmaxl[0], wmaxl[1]), fmaxf(wmaxl[2], wmaxl[3]));
  ((float2*)ve)[tid]  = (float2){ __expf(fv.x - F2max),        __expf(fv.y - F2max) };
  ((float2*)vhe)[tid] = (float2){ __expf(0.2f*(fv.x - F2max)), __expf(0.2f*(fv.y - F2max)) };
  __syncthreads();     // tables visible to all waves; no further barriers

  // ---- finish adj: wave-private mask words (kt = l&15, row = t*4+(l>>4)) -
  unsigned* mw = maskws + w*272;
#define GAT_CONV(SRC, T) { unsigned wd = 0u; \
  _Pragma("unroll") for (int i = 0; i < 8; ++i) { \
    if ((int)SRC[i].x > 0) wd |= 1u << (4*i); \
    if ((int)SRC[i].y > 0) wd |= 2u << (4*i); \
    if ((int)SRC[i].z > 0) wd |= 4u << (4*i); \
    if ((int)SRC[i].w > 0) wd |= 8u << (4*i); } \
  mw[(l & 15)*17 + (T)*4 + (l >> 4)] = wd; }
  GAT_CONV(A0, 0)
  #pragma unroll
  for (int i = 0; i < 8; ++i) A0[i] = ablk[1024 + l*8 + i];
  GAT_CONV(A1, 1)
  #pragma unroll
  for (int i = 0; i < 8; ++i) A1[i] = ablk[1536 + l*8 + i];
  GAT_CONV(A0, 2)
  GAT_CONV(A1, 3)
#undef GAT_CONV

  // ---- fused main loop: p (A-frag, in-register) -> 5 MFMAs per kt --------
  const float f1v = f1l[w*16 + r];
  const float tR  = f1v + F2max;
  const float M   = fmaxf(tR, 0.2f*tR);
  const float u   = __expf(tR - M);
  const float uh  = __expf(0.2f*tR - M);
  const u16* wb   = whB + (size_t)bt*32768 + l*8;
  i16x8 bones;
  #pragma unroll
  for (int e = 0; e < 8; ++e) bones[e] = (short)0x3F80;  // bf16 1.0
  fx4 acc0 = {0,0,0,0}, acc1 = {0,0,0,0}, acc2 = {0,0,0,0}, acc3 = {0,0,0,0};
  fx4 accS = {0,0,0,0};

  #pragma unroll
  for (int kt = 0; kt < 16; ++kt) {
    const unsigned mword = mw[kt*17 + r];
    const unsigned mb    = (mword >> (8*q)) & 0xFFu;
    const fx4 a0 = ((const fx4*)ve)[kt*8 + 2*q];
    const fx4 a1 = ((const fx4*)ve)[kt*8 + 2*q + 1];
    const fx4 h0 = ((const fx4*)vhe)[kt*8 + 2*q];
    const fx4 h1 = ((const fx4*)vhe)[kt*8 + 2*q + 1];
    const uint2 mA = lutl[mb & 15u];
    const uint2 mB = lutl[mb >> 4];
    uint4 pw;
    pw.x = pk2(fmaxf(u*a0[0], uh*h0[0]), fmaxf(u*a0[1], uh*h0[1])) & mA.x;
    pw.y = pk2(fmaxf(u*a0[2], uh*h0[2]), fmaxf(u*a0[3], uh*h0[3])) & mA.y;
    pw.z = pk2(fmaxf(u*a1[0], uh*h1[0]), fmaxf(u*a1[1], uh*h1[1])) & mB.x;
    pw.w = pk2(fmaxf(u*a1[2], uh*h1[2]), fmaxf(u*a1[3], uh*h1[3])) & mB.y;
    const i16x8 paf = *(const i16x8*)&pw;
    const u16* bp = wb + kt*2048;
    const i16x8 b0 = *(const i16x8*)(bp);
    const i16x8 b1 = *(const i16x8*)(bp + 512);
    const i16x8 b2 = *(const i16x8*)(bp + 1024);
    const i16x8 b3 = *(const i16x8*)(bp + 1536);
    acc0 = __builtin_amdgcn_mfma_f32_16x16x32_bf16(paf, b0, acc0, 0, 0, 0);
    acc1 = __builtin_amdgcn_mfma_f32_16x16x32_bf16(paf, b1, acc1, 0, 0, 0);
    acc2 = __builtin_amdgcn_mfma_f32_16x16x32_bf16(paf, b2, acc2, 0, 0, 0);
    acc3 = __builtin_amdgcn_mfma_f32_16x16x32_bf16(paf, b3, acc3, 0, 0, 0);
    accS = __builtin_amdgcn_mfma_f32_16x16x32_bf16(paf, bones, accS, 0, 0, 0);
  }

  // ---- exact fallback (underflow-risk or all-masked rows; ~never) --------
  const bool bad = (accS[0] < 1e-30f) || (accS[1] < 1e-30f) ||
                   (accS[2] < 1e-30f) || (accS[3] < 1e-30f);
  if (__any((int)bad)) {
    float mx = NEG_INF_F;
    #pragma unroll
    for (int kt = 0; kt < 16; ++kt) {
      const unsigned mb = (mw[kt*17 + r] >> (8*q)) & 0xFFu;
      const fx4 g0v = ((const fx4*)f2l)[kt*8 + 2*q];
      const fx4 g1v = ((const fx4*)f2l)[kt*8 + 2*q + 1];
      mx = fmaxf(mx, (mb &   1u) ? g0v[0] : NEG_INF_F);
      mx = fmaxf(mx, (mb &   2u) ? g0v[1] : NEG_INF_F);
      mx = fmaxf(mx, (mb &   4u) ? g0v[2] : NEG_INF_F);
      mx = fmaxf(mx, (mb &   8u) ? g0v[3] : NEG_INF_F);
      mx = fmaxf(mx, (mb &  16u) ? g1v[0] : NEG_INF_F);
      mx = fmaxf(mx, (mb &  32u) ? g1v[1] : NEG_INF_F);
      mx = fmaxf(mx, (mb &  64u) ? g1v[2] : NEG_INF_F);
      mx = fmaxf(mx, (mb & 128u) ? g1v[3] : NEG_INF_F);
    }
    mx = fmaxf(mx, __shfl_xor(mx, 16));
    mx = fmaxf(mx, __shfl_xor(mx, 32));
    const float tM = f1v + mx;
    const float Mc = fmaxf(tM, 0.2f*tM);
    const float Mf = (mx == NEG_INF_F) ? NEG_INF_F : Mc;
    acc0 = acc1 = acc2 = acc3 = accS = (fx4){0,0,0,0};
    #pragma unroll
    for (int kt = 0; kt < 16; ++kt) {
      const unsigned mb = (mw[kt*17 + r] >> (8*q)) & 0xFFu;
      const fx4 g0v = ((const fx4*)f2l)[kt*8 + 2*q];
      const fx4 g1v = ((const fx4*)f2l)[kt*8 + 2*q + 1];
      float pv[8];
#define GAT_S(idx, bb_, ff) { float s = f1v + (ff); float lr = fmaxf(s, 0.2f*s); \
      float ee = (bb_) ? lr : NEG_INF_F; pv[idx] = __expf(ee - Mf); }
      GAT_S(0, mb &   1u, g0v[0]) GAT_S(1, mb &   2u, g0v[1])
      GAT_S(2, mb &   4u, g0v[2]) GAT_S(3, mb &   8u, g0v[3])
      GAT_S(4, mb &  16u, g1v[0]) GAT_S(5, mb &  32u, g1v[1])
      GAT_S(6, mb &  64u, g1v[2]) GAT_S(7, mb & 128u, g1v[3])
#undef GAT_S
      uint4 pw;
      pw.x = pk2(pv[0], pv[1]); pw.y = pk2(pv[2], pv[3]);
      pw.z = pk2(pv[4], pv[5]); pw.w = pk2(pv[6], pv[7]);
      const i16x8 paf = *(const i16x8*)&pw;
      const u16* bp = wb + kt*2048;
      const i16x8 b0 = *(const i16x8*)(bp);
      const i16x8 b1 = *(const i16x8*)(bp + 512);
      const i16x8 b2 = *(const i16x8*)(bp + 1024);
      const i16x8 b3 = *(const i16x8*)(bp + 1536);
      acc0 = __builtin_amdgcn_mfma_f32_16x16x32_bf16(paf, b0, acc0, 0, 0, 0);
      acc1 = __builtin_amdgcn_mfma_f32_16x16x32_bf16(paf, b1, acc1, 0, 0, 0);
      acc2 = __builtin_amdgcn_mfma_f32_16x16x32_bf16(paf, b2, acc2, 0, 0, 0);
      acc3 = __builtin_amdgcn_mfma_f32_16x16x32_bf16(paf, b3, acc3, 0, 0, 0);
      accS = __builtin_amdgcn_mfma_f32_16x16x32_bf16(paf, bones, accS, 0, 0, 0);
    }
  }

  // ---- epilogue: normalize + ELU.  C/D: col = l&15, row = q*4 + rr -------
  float* op = out + ((size_t)bt*512 + g0 + w*16) * 64;
  #pragma unroll
  for (int rr = 0; rr < 4; ++rr) {
    const float rs = 1.0f / accS[rr];
    float v0 = acc0[rr] * rs; v0 = v0 > 0.f ? v0 : expm1f(v0);
    float v1 = acc1[rr] * rs; v1 = v1 > 0.f ? v1 : expm1f(v1);
    float v2 = acc2[rr] * rs; v2 = v2 > 0.f ? v2 : expm1f(v2);
    float v3 = acc3[rr] * rs; v3 = v3 > 0.f ? v3 : expm1f(v3);
    float* o = op + (q*4 + rr)*64 + r;
    o[ 0] = v0;
    o[16] = v1;
    o[32] = v2;
    o[48] = v3;
  }
}

// ---------------------------------------------------------------------------
extern "C" void kernel_launch(void* const* d_in, const int* in_sizes, int n_in,
                              void* d_out, int out_size, void* d_ws, size_t ws_size,
                              hipStream_t stream) {
  const float* input = (const float*)d_in[0];   // (8,64,12,512) f32
  const int*   adj   = (const int*)  d_in[1];   // (8,12,512,512) i32
  const float* W     = (const float*)d_in[2];   // (64,64) f32
  const float* Avec  = (const float*)d_in[3];   // (128,1) f32
  float* out = (float*)d_out;

  // ws: whB bf16 (6,291,456 B) | f1 (196,608) | f2 (196,608)
  char* ws = (char*)d_ws;
  u16*   whB = (u16*)ws;
  float* f1w = (float*)(ws + 6291456);
  float* f2w = (float*)(ws + 6291456 + 196608);

  gat_prep<<<dim3(2, 96), 256, 0, stream>>>(input, W, Avec, whB, f1w, f2w);
  gat_attn<<<768, 256, 0, stream>>>(adj, whB, f1w, f2w, out);
}

// Round 12
// 70.854 us; speedup vs baseline: 1.6595x; 1.6595x over previous
//
#include <hip/hip_runtime.h>
#include <hip/hip_bf16.h>

typedef float fx4 __attribute__((ext_vector_type(4)));
typedef short i16x8 __attribute__((ext_vector_type(8)));
typedef unsigned short u16;

#define NEG_INF_F (-9.0e15f)

__device__ inline u16 f2bf(float v){
  __hip_bfloat16 h = __float2bfloat16(v);
  return *reinterpret_cast<u16*>(&h);
}
__device__ inline unsigned pk2(float lo, float hi){
  return (unsigned)f2bf(lo) | ((unsigned)f2bf(hi) << 16);
}

// ---------------------------------------------------------------------------
// Kernel 1: Wh = x @ W (fp32), f1 = Wh@a1, f2 = Wh@a2 (fp32).
// Wh emitted bf16 in MFMA B-fragment-linear layout whB[bt][kt][ct][lane][8].
// grid (2, 96), 256 threads; thread = one node n.  (proven, unchanged)
// ---------------------------------------------------------------------------
__global__ __launch_bounds__(256) void gat_prep(
    const float* __restrict__ input,   // (8,64,12,512)
    const float* __restrict__ W,       // (64,64)
    const float* __restrict__ Avec,    // (128,1)
    u16*   __restrict__ whB,           // (96,16,4,512) bf16 fragment-linear
    float* __restrict__ f1w,           // (96,512)
    float* __restrict__ f2w)           // (96,512)
{
  __shared__ float Wl[64*64];
  __shared__ float Al[128];
  __shared__ u16   Rp[16384];
  const int tid = threadIdx.x;
  const int bt  = blockIdx.y;
  const int b   = bt / 12, t = bt % 12;
  const int xb  = blockIdx.x;
  const int n   = xb * 256 + tid;

  {
    const fx4* src = (const fx4*)W;
    fx4* dst = (fx4*)Wl;
    #pragma unroll
    for (int i = 0; i < 4; ++i) dst[tid + 256*i] = src[tid + 256*i];
    if (tid < 32) ((fx4*)Al)[tid] = ((const fx4*)Avec)[tid];
  }
  __syncthreads();

  const float* xp = input + ((size_t)b*64*12 + t) * 512 + n;

  fx4 acc[16];
  #pragma unroll
  for (int i = 0; i < 16; ++i) acc[i] = (fx4){0.f,0.f,0.f,0.f};

  #pragma unroll 8
  for (int f = 0; f < 64; ++f) {
    float xv = xp[(size_t)f * 6144];
    const fx4* wr = (const fx4*)(Wl + f*64);
    #pragma unroll
    for (int o4 = 0; o4 < 16; ++o4) acc[o4] += xv * wr[o4];
  }

  float s1 = 0.f, s2 = 0.f;
  #pragma unroll
  for (int o4 = 0; o4 < 16; ++o4) {
    fx4 v  = acc[o4];
    fx4 w1 = ((const fx4*)Al)[o4];
    fx4 w2 = ((const fx4*)Al)[o4 + 16];
    s1 += v[0]*w1[0] + v[1]*w1[1] + v[2]*w1[2] + v[3]*w1[3];
    s2 += v[0]*w2[0] + v[1]*w2[1] + v[2]*w2[2] + v[3]*w2[3];
  }
  f1w[bt*512 + n] = s1;
  f2w[bt*512 + n] = s2;

  const int ktl  = (n >> 5) & 7;
  const int q    = (n >> 3) & 3;
  const int e    = n & 7;
  const int rowb = ktl*2048 + q*128 + e;
  #pragma unroll
  for (int o4 = 0; o4 < 16; ++o4) {
    #pragma unroll
    for (int c = 0; c < 4; ++c) {
      const int o = o4*4 + c;
      Rp[rowb + (o >> 4)*512 + (o & 15)*8] = f2bf(acc[o4][c]);
    }
  }
  __syncthreads();

  uint4* dst = (uint4*)(whB + ((size_t)bt*16 + xb*8) * 2048);
  const uint4* src = (const uint4*)Rp;
  #pragma unroll
  for (int i = 0; i < 8; ++i) dst[tid + 256*i] = src[tid + 256*i];
}

// ---------------------------------------------------------------------------
// Kernel 2: barrier-free wave-autonomous attn (R11 design, spill fixed).
// grid 768, 256 threads = 4 waves; wave owns 16 rows end-to-end; after a
// 2-barrier table prologue waves never sync. p is computed directly in MFMA
// A-fragment layout and consumed by 4 PV MFMAs + 1 ones-MFMA (row sums in
// the exact C/D lanes the epilogue needs). NO __launch_bounds__ min-waves:
// R11's (256,4) forced 64 VGPRs -> 173MB scratch spill (measured); the
// kernel needs ~150-190 VGPRs. LDS 11.3KB is not the occupancy limiter.
// ---------------------------------------------------------------------------
__global__ __launch_bounds__(256) void gat_attn(
    const int*   __restrict__ adj,   // (96,512,512)
    const u16*   __restrict__ whB,   // (96,16,4,512) bf16 fragment-linear
    const float* __restrict__ f1w,
    const float* __restrict__ f2w,
    float*       __restrict__ out)   // (96,512,64)
{
  __shared__ float ve[512], vhe[512], f2l[512];
  __shared__ float f1l[64];
  __shared__ float wmaxl[4];
  __shared__ uint2 lutl[16];
  __shared__ unsigned maskws[4*272];   // per-wave [kt][row] u32, stride 17

  const int tid = threadIdx.x;
  const int l   = tid & 63;
  const int w   = tid >> 6;
  const int id  = blockIdx.x;
  const int bt  = id >> 3;
  const int g0  = (id & 7) * 64;       // block row base within bt
  const int r   = l & 15, q = l >> 4;

  // ---- issue first 2 adj rounds immediately (hide under prologue) --------
  const uint4* ablk = (const uint4*)(adj + ((size_t)bt*512 + g0 + w*16)*512);
  uint4 A0[8], A1[8];
  #pragma unroll
  for (int i = 0; i < 8; ++i) A0[i] = ablk[l*8 + i];
  #pragma unroll
  for (int i = 0; i < 8; ++i) A1[i] = ablk[512 + l*8 + i];

  // ---- prologue: f2 (+block max), f1, LUT; then exp tables ---------------
  float2 fv = ((const float2*)(f2w + bt*512))[tid];
  ((float2*)f2l)[tid] = fv;
  float m2 = fmaxf(fv.x, fv.y);
  #pragma unroll
  for (int off = 32; off >= 1; off >>= 1) m2 = fmaxf(m2, __shfl_xor(m2, off));
  if (l == 0) wmaxl[w] = m2;
  if (tid < 64) f1l[tid] = f1w[bt*512 + g0 + tid];
  if (tid < 16) {
    const unsigned nb = tid;
    lutl[tid] = (uint2){ ((nb&1u)?0xFFFFu:0u) | ((nb&2u)?0xFFFF0000u:0u),
                         ((nb&4u)?0xFFFFu:0u) | ((nb&8u)?0xFFFF0000u:0u) };
  }
  __syncthreads();
  const float F2max = fmaxf(fmaxf(wmaxl[0], wmaxl[1]), fmaxf(wmaxl[2], wmaxl[3]));
  ((float2*)ve)[tid]  = (float2){ __expf(fv.x - F2max),        __expf(fv.y - F2max) };
  ((float2*)vhe)[tid] = (float2){ __expf(0.2f*(fv.x - F2max)), __expf(0.2f*(fv.y - F2max)) };
  __syncthreads();     // tables visible to all waves; no further barriers

  // ---- finish adj: wave-private mask words (kt = l&15, row = t*4+(l>>4)) -
  unsigned* mw = maskws + w*272;
#define GAT_CONV(SRC, T) { unsigned wd = 0u; \
  _Pragma("unroll") for (int i = 0; i < 8; ++i) { \
    if ((int)SRC[i].x > 0) wd |= 1u << (4*i); \
    if ((int)SRC[i].y > 0) wd |= 2u << (4*i); \
    if ((int)SRC[i].z > 0) wd |= 4u << (4*i); \
    if ((int)SRC[i].w > 0) wd |= 8u << (4*i); } \
  mw[(l & 15)*17 + (T)*4 + (l >> 4)] = wd; }
  GAT_CONV(A0, 0)
  #pragma unroll
  for (int i = 0; i < 8; ++i) A0[i] = ablk[1024 + l*8 + i];
  GAT_CONV(A1, 1)
  #pragma unroll
  for (int i = 0; i < 8; ++i) A1[i] = ablk[1536 + l*8 + i];
  GAT_CONV(A0, 2)
  GAT_CONV(A1, 3)
#undef GAT_CONV

  // ---- fused main loop: p (A-frag, in-register) -> 5 MFMAs per kt --------
  const float f1v = f1l[w*16 + r];
  const float tR  = f1v + F2max;
  const float M   = fmaxf(tR, 0.2f*tR);
  const float u   = __expf(tR - M);
  const float uh  = __expf(0.2f*tR - M);
  const u16* wb   = whB + (size_t)bt*32768 + l*8;
  i16x8 bones;
  #pragma unroll
  for (int e = 0; e < 8; ++e) bones[e] = (short)0x3F80;  // bf16 1.0
  fx4 acc0 = {0,0,0,0}, acc1 = {0,0,0,0}, acc2 = {0,0,0,0}, acc3 = {0,0,0,0};
  fx4 accS = {0,0,0,0};

  #pragma unroll
  for (int kt = 0; kt < 16; ++kt) {
    const unsigned mword = mw[kt*17 + r];
    const unsigned mb    = (mword >> (8*q)) & 0xFFu;
    const fx4 a0 = ((const fx4*)ve)[kt*8 + 2*q];
    const fx4 a1 = ((const fx4*)ve)[kt*8 + 2*q + 1];
    const fx4 h0 = ((const fx4*)vhe)[kt*8 + 2*q];
    const fx4 h1 = ((const fx4*)vhe)[kt*8 + 2*q + 1];
    const uint2 mA = lutl[mb & 15u];
    const uint2 mB = lutl[mb >> 4];
    uint4 pw;
    pw.x = pk2(fmaxf(u*a0[0], uh*h0[0]), fmaxf(u*a0[1], uh*h0[1])) & mA.x;
    pw.y = pk2(fmaxf(u*a0[2], uh*h0[2]), fmaxf(u*a0[3], uh*h0[3])) & mA.y;
    pw.z = pk2(fmaxf(u*a1[0], uh*h1[0]), fmaxf(u*a1[1], uh*h1[1])) & mB.x;
    pw.w = pk2(fmaxf(u*a1[2], uh*h1[2]), fmaxf(u*a1[3], uh*h1[3])) & mB.y;
    const i16x8 paf = *(const i16x8*)&pw;
    const u16* bp = wb + kt*2048;
    const i16x8 b0 = *(const i16x8*)(bp);
    const i16x8 b1 = *(const i16x8*)(bp + 512);
    const i16x8 b2 = *(const i16x8*)(bp + 1024);
    const i16x8 b3 = *(const i16x8*)(bp + 1536);
    acc0 = __builtin_amdgcn_mfma_f32_16x16x32_bf16(paf, b0, acc0, 0, 0, 0);
    acc1 = __builtin_amdgcn_mfma_f32_16x16x32_bf16(paf, b1, acc1, 0, 0, 0);
    acc2 = __builtin_amdgcn_mfma_f32_16x16x32_bf16(paf, b2, acc2, 0, 0, 0);
    acc3 = __builtin_amdgcn_mfma_f32_16x16x32_bf16(paf, b3, acc3, 0, 0, 0);
    accS = __builtin_amdgcn_mfma_f32_16x16x32_bf16(paf, bones, accS, 0, 0, 0);
  }

  // ---- exact fallback (underflow-risk or all-masked rows; ~never) --------
  const bool bad = (accS[0] < 1e-30f) || (accS[1] < 1e-30f) ||
                   (accS[2] < 1e-30f) || (accS[3] < 1e-30f);
  if (__any((int)bad)) {
    float mx = NEG_INF_F;
    #pragma unroll
    for (int kt = 0; kt < 16; ++kt) {
      const unsigned mb = (mw[kt*17 + r] >> (8*q)) & 0xFFu;
      const fx4 g0v = ((const fx4*)f2l)[kt*8 + 2*q];
      const fx4 g1v = ((const fx4*)f2l)[kt*8 + 2*q + 1];
      mx = fmaxf(mx, (mb &   1u) ? g0v[0] : NEG_INF_F);
      mx = fmaxf(mx, (mb &   2u) ? g0v[1] : NEG_INF_F);
      mx = fmaxf(mx, (mb &   4u) ? g0v[2] : NEG_INF_F);
      mx = fmaxf(mx, (mb &   8u) ? g0v[3] : NEG_INF_F);
      mx = fmaxf(mx, (mb &  16u) ? g1v[0] : NEG_INF_F);
      mx = fmaxf(mx, (mb &  32u) ? g1v[1] : NEG_INF_F);
      mx = fmaxf(mx, (mb &  64u) ? g1v[2] : NEG_INF_F);
      mx = fmaxf(mx, (mb & 128u) ? g1v[3] : NEG_INF_F);
    }
    mx = fmaxf(mx, __shfl_xor(mx, 16));
    mx = fmaxf(mx, __shfl_xor(mx, 32));
    const float tM = f1v + mx;
    const float Mc = fmaxf(tM, 0.2f*tM);
    const float Mf = (mx == NEG_INF_F) ? NEG_INF_F : Mc;
    acc0 = acc1 = acc2 = acc3 = accS = (fx4){0,0,0,0};
    #pragma unroll
    for (int kt = 0; kt < 16; ++kt) {
      const unsigned mb = (mw[kt*17 + r] >> (8*q)) & 0xFFu;
      const fx4 g0v = ((const fx4*)f2l)[kt*8 + 2*q];
      const fx4 g1v = ((const fx4*)f2l)[kt*8 + 2*q + 1];
      float pv[8];
#define GAT_S(idx, bb_, ff) { float s = f1v + (ff); float lr = fmaxf(s, 0.2f*s); \
      float ee = (bb_) ? lr : NEG_INF_F; pv[idx] = __expf(ee - Mf); }
      GAT_S(0, mb &   1u, g0v[0]) GAT_S(1, mb &   2u, g0v[1])
      GAT_S(2, mb &   4u, g0v[2]) GAT_S(3, mb &   8u, g0v[3])
      GAT_S(4, mb &  16u, g1v[0]) GAT_S(5, mb &  32u, g1v[1])
      GAT_S(6, mb &  64u, g1v[2]) GAT_S(7, mb & 128u, g1v[3])
#undef GAT_S
      uint4 pw;
      pw.x = pk2(pv[0], pv[1]); pw.y = pk2(pv[2], pv[3]);
      pw.z = pk2(pv[4], pv[5]); pw.w = pk2(pv[6], pv[7]);
      const i16x8 paf = *(const i16x8*)&pw;
      const u16* bp = wb + kt*2048;
      const i16x8 b0 = *(const i16x8*)(bp);
      const i16x8 b1 = *(const i16x8*)(bp + 512);
      const i16x8 b2 = *(const i16x8*)(bp + 1024);
      const i16x8 b3 = *(const i16x8*)(bp + 1536);
      acc0 = __builtin_amdgcn_mfma_f32_16x16x32_bf16(paf, b0, acc0, 0, 0, 0);
      acc1 = __builtin_amdgcn_mfma_f32_16x16x32_bf16(paf, b1, acc1, 0, 0, 0);
      acc2 = __builtin_amdgcn_mfma_f32_16x16x32_bf16(paf, b2, acc2, 0, 0, 0);
      acc3 = __builtin_amdgcn_mfma_f32_16x16x32_bf16(paf, b3, acc3, 0, 0, 0);
      accS = __builtin_amdgcn_mfma_f32_16x16x32_bf16(paf, bones, accS, 0, 0, 0);
    }
  }

  // ---- epilogue: normalize + ELU.  C/D: col = l&15, row = q*4 + rr -------
  float* op = out + ((size_t)bt*512 + g0 + w*16) * 64;
  #pragma unroll
  for (int rr = 0; rr < 4; ++rr) {
    const float rs = 1.0f / accS[rr];
    float v0 = acc0[rr] * rs; v0 = v0 > 0.f ? v0 : expm1f(v0);
    float v1 = acc1[rr] * rs; v1 = v1 > 0.f ? v1 : expm1f(v1);
    float v2 = acc2[rr] * rs; v2 = v2 > 0.f ? v2 : expm1f(v2);
    float v3 = acc3[rr] * rs; v3 = v3 > 0.f ? v3 : expm1f(v3);
    float* o = op + (q*4 + rr)*64 + r;
    o[ 0] = v0;
    o[16] = v1;
    o[32] = v2;
    o[48] = v3;
  }
}

// ---------------------------------------------------------------------------
extern "C" void kernel_launch(void* const* d_in, const int* in_sizes, int n_in,
                              void* d_out, int out_size, void* d_ws, size_t ws_size,
                              hipStream_t stream) {
  const float* input = (const float*)d_in[0];   // (8,64,12,512) f32
  const int*   adj   = (const int*)  d_in[1];   // (8,12,512,512) i32
  const float* W     = (const float*)d_in[2];   // (64,64) f32
  const float* Avec  = (const float*)d_in[3];   // (128,1) f32
  float* out = (float*)d_out;

  // ws: whB bf16 (6,291,456 B) | f1 (196,608) | f2 (196,608)
  char* ws = (char*)d_ws;
  u16*   whB = (u16*)ws;
  float* f1w = (float*)(ws + 6291456);
  float* f2w = (float*)(ws + 6291456 + 196608);

  gat_prep<<<dim3(2, 96), 256, 0, stream>>>(input, W, Avec, whB, f1w, f2w);
  gat_attn<<<768, 256, 0, stream>>>(adj, whB, f1w, f2w, out);
}